// Round 8
// baseline (920.269 us; speedup 1.0000x reference)
//
#include <hip/hip_runtime.h>
#include <cstdint>
#include <cstddef>

// =====================================================================
// Network_28862180229296: 3-layer heterogeneous message passing + pooling + MLP
//
// Transposed formulation: hs_j = sum_k (A_k x_i) @ W_k   (segment-sum is linear)
//
// R16 structure:
//  - k_fused: 8-edge MONOLITH batch with NO VGPR cap (launch_bounds(64) only).
//    R13 proved the monolith wants ~140 VGPR (spilled under cap 128);
//    R15 proved a 2-stage source structure lets the compiler dodge to 84 VGPR
//    (unrealized pipeline). This is the untested cell: forced depth + legal
//    register budget. Spill tripwire: WRITE_SIZE must stay ~38.75 MB.
//  - tail merged: k_pool2 absorbed into k_fc1 (per-block redundant reduction,
//    bit-identical order); k_fc2+k_rest merged into k_tail2 (8-pass fc2
//    replicating the old 16x16 split exactly). 9 -> 7 launches.
//  - k_prep merged cvt/cvtw/ptr; k_pool1 PB=128 uint4+shfl (R12).
// =====================================================================

namespace {

constexpr int NRr[5]  = {50000, 100000, 100000, 40000, 20000};
constexpr int PI[15]  = {0,1,2,3,4,0,0,0,0,1,1,1,2,2,3};
constexpr long long EOFF[15] = {0,400000,1200000,2000000,2320000,2480000,3280000,4080000,4400000,4560000,5360000,5680000,5840000,6160000,6320000};
constexpr int EK[15]  = {400000,800000,800000,320000,160000,800000,800000,320000,160000,800000,320000,160000,320000,160000,160000};
constexpr int POFF[15] = {0,50001,150002,250003,290004,310005,410006,510007,550008,570009,670010,710011,730012,770013,790014};
constexpr int PTR_TOT  = 810015;
constexpr int XOFF[5]  = {0,50000,150000,250000,290000};
constexpr int XROWS    = 310000;
constexpr int NPJ[5]    = {1,2,3,4,5};
constexpr int POJ[5][5] = {{0,0,0,0,0},{1,5,0,0,0},{2,6,9,0,0},{3,7,10,12,0},{4,8,11,13,14}};
// 16-row tiles, heavy-first (rank 4: 40 e/row ... rank 0: 8 e/row)
constexpr int TCUM[6]  = {0,1250,3750,10000,16250,19375};
constexpr int TRANK[5] = {4,3,2,1,0};
constexpr int FUSED_BLOCKS = 19375;

constexpr int PB = 128;   // pooling partial blocks per rank (640 blocks total)

// merged prologue grid sections
constexpr int CVT_BLOCKS  = (XROWS * 16) / 256;          // 19375 (exact)
constexpr int CVTW_BLOCKS = (3 * 15 * 4096) / 256;       // 720 (exact)
constexpr int PTR_BLOCKS  = (PTR_TOT + 255) / 256;       // 3165
constexpr int PREP_BLOCKS = CVT_BLOCKS + CVTW_BLOCKS + PTR_BLOCKS;

// ---- workspace layout (bytes) ----
constexpr size_t WS_B16IN = 0;                      // ushort[310000*64] = 39,680,000
constexpr size_t WS_B16X  = 39680000;
constexpr size_t WS_B16Y  = 79360000;
constexpr size_t WS_PTR   = 119040000;              // int[810015] = 3,240,060
constexpr size_t WS_WT    = 122280064;              // ushort[3*15*4096] = 368,640
constexpr size_t WS_PSUM  = 122648704;              // double[5*PB*64]
constexpr size_t WS_PSQ   = WS_PSUM + (size_t)5*PB*64*8;
constexpr size_t WS_PMAX  = WS_PSQ  + (size_t)5*PB*64*8;
constexpr size_t WS_PMIN  = WS_PMAX + (size_t)5*PB*64*4;
constexpr size_t WS_H1    = WS_PMIN + (size_t)5*PB*64*4;  // float[512]
constexpr size_t WS_NEEDED = WS_H1 + 2048;

struct XP  { const float* p[5]; };
struct XPB { const unsigned short* p[5]; };

} // namespace

typedef __attribute__((ext_vector_type(8))) short short8;
typedef __attribute__((ext_vector_type(4))) float f32x4;

// ---------------------------------------------------------------------
// bf16 helpers (RNE)
// ---------------------------------------------------------------------
static __device__ __forceinline__ unsigned int rne_bf16(float x) {
    unsigned int b = __float_as_uint(x);
    return (b + 0x7fffu + ((b >> 16) & 1u)) >> 16;
}
static __device__ __forceinline__ float4 bf16x4_to_f4(uint2 u) {
    float4 f;
    f.x = __uint_as_float(u.x << 16);
    f.y = __uint_as_float(u.x & 0xffff0000u);
    f.z = __uint_as_float(u.y << 16);
    f.w = __uint_as_float(u.y & 0xffff0000u);
    return f;
}
static __device__ __forceinline__ uint2 f4_to_bf16x4(float4 v) {
    uint2 st;
    st.x = rne_bf16(v.x) | (rne_bf16(v.y) << 16);
    st.y = rne_bf16(v.z) | (rne_bf16(v.w) << 16);
    return st;
}
static __device__ __forceinline__ void fma4(float4& a, float s, const float4& b) {
    a.x += s * b.x; a.y += s * b.y; a.z += s * b.z; a.w += s * b.w;
}
static __device__ __forceinline__ void fma8(float4& alo, float4& ahi, float s, uint4 g) {
    fma4(alo, s, bf16x4_to_f4(make_uint2(g.x, g.y)));
    fma4(ahi, s, bf16x4_to_f4(make_uint2(g.z, g.w)));
}
static __device__ __forceinline__ short8 pack_af(float4 lo, float4 hi) {
    uint2 pa = f4_to_bf16x4(lo);
    uint2 pb = f4_to_bf16x4(hi);
    short8 af;
    ((unsigned int*)&af)[0] = pa.x;
    ((unsigned int*)&af)[1] = pa.y;
    ((unsigned int*)&af)[2] = pb.x;
    ((unsigned int*)&af)[3] = pb.y;
    return af;
}

// ---------------------------------------------------------------------
__global__ void k_diag(float* __restrict__ out, float v) {
    out[0] = v;
    out[1] = 0.f;
}

// ---------------------------------------------------------------------
// 0) merged prologue: [cvt inputs -> bf16 | transpose W -> bf16 | CSR row_ptr]
// ---------------------------------------------------------------------
__global__ __launch_bounds__(256) void k_prep(XP xin, unsigned short* __restrict__ b16,
                                              const float* __restrict__ Wh,
                                              unsigned short* __restrict__ WT,
                                              const int* __restrict__ rows,
                                              int* __restrict__ rptr) {
    int bx = blockIdx.x;
    if (bx < CVT_BLOCKS) {
        int q = bx * 256 + threadIdx.x;   // quad index (4 channels); grid exact
        int row = q >> 4;
        int rank = 0;
#pragma unroll
        for (int t = 1; t < 5; ++t) if (row >= XOFF[t]) rank = t;
        const float* src = xin.p[rank] + (size_t)(row - XOFF[rank]) * 64 + (q & 15) * 4;
        float4 v = *(const float4*)src;
        ((uint2*)b16)[q] = f4_to_bf16x4(v);
    } else if (bx < CVT_BLOCKS + CVTW_BLOCKS) {
        int tid = (bx - CVT_BLOCKS) * 256 + threadIdx.x;   // grid exact
        int lp = tid >> 12;
        int nk_ = tid & 4095;
        int n = nk_ >> 6;
        int k = nk_ & 63;
        float w = Wh[(size_t)lp * 4096 + k * 64 + n];
        WT[tid] = (unsigned short)rne_bf16(w);
    } else {
        int tid = (bx - CVT_BLOCKS - CVTW_BLOCKS) * 256 + threadIdx.x;
        if (tid >= PTR_TOT) return;
        int k = 0;
#pragma unroll
        for (int t = 1; t < 15; ++t) if (tid >= POFF[t]) k = t;
        int r = tid - POFF[k];
        const int* rb = rows + EOFF[k];
        int lo = 0, hi = EK[k];
        while (lo < hi) {
            int mid = (lo + hi) >> 1;
            if (rb[mid] < r) lo = mid + 1; else hi = mid;
        }
        rptr[tid] = lo;
    }
}

// ---------------------------------------------------------------------
// 2) fused aggregate (reg-direct bf16 gather) + MFMA GEMM + residual + relu
//    one wave per 16-row tile; 8-edge monolith batch (16 uint4 + 16 index
//    loads in flight). NO VGPR cap: allocator free to take ~140 (vs R13's
//    cap-128 spill). Spill tripwire: WRITE_SIZE ~38.75 MB.
// ---------------------------------------------------------------------
__global__ __launch_bounds__(64) void k_fused(XPB xp,
                                              const int* __restrict__ cols,
                                              const float* __restrict__ vals,
                                              const int* __restrict__ rptr,
                                              const unsigned short* __restrict__ WT,
                                              unsigned short* __restrict__ xout,
                                              int layer) {
    __shared__ float C[16 * 65];   // 4160 B, C-epilogue transpose only

    int b = blockIdx.x;
    int seg = 0;
#pragma unroll
    for (int t = 1; t < 5; ++t) if (b >= TCUM[t]) seg = t;
    int j  = TRANK[seg];
    int r0 = (b - TCUM[seg]) * 16;

    int lane = threadIdx.x;
    int m    = lane & 15;          // owned output row (A-frag m index / B-frag n index)
    int quad = lane >> 4;          // 0..3
    int s8   = quad * 8;           // channel-slice base (shorts) within a K-half

    f32x4 d0 = {0.f,0.f,0.f,0.f};
    f32x4 d1 = d0, d2 = d0, d3 = d0;

    const unsigned short* WTl = WT + (size_t)layer * 15 * 4096;
    int nk = NPJ[j];
    for (int kc = 0; kc < nk; ++kc) {
        int pk = POJ[j][kc];
        const unsigned short* __restrict__ xsrc = xp.p[PI[pk]];
        const int*   __restrict__ cb = cols + EOFF[pk];
        const float* __restrict__ vb = vals + EOFF[pk];
        const int*   __restrict__ rp = rptr + POFF[pk];

        // ---- gather this pair: 16 rows concurrently, 8-edge batch per row ----
        int ps = rp[r0 + m];
        int pe = rp[r0 + m + 1];
        float4 a0lo = make_float4(0.f,0.f,0.f,0.f), a0hi = a0lo;  // K-half 0
        float4 a1lo = a0lo, a1hi = a0lo;                          // K-half 1
        int e = ps;
        for (; e + 7 < pe; e += 8) {
            int   c0 = cb[e];
            int   c1 = cb[e + 1];
            int   c2 = cb[e + 2];
            int   c3 = cb[e + 3];
            int   c4 = cb[e + 4];
            int   c5 = cb[e + 5];
            int   c6 = cb[e + 6];
            int   c7 = cb[e + 7];
            float v0 = vb[e];
            float v1 = vb[e + 1];
            float v2 = vb[e + 2];
            float v3 = vb[e + 3];
            float v4 = vb[e + 4];
            float v5 = vb[e + 5];
            float v6 = vb[e + 6];
            float v7 = vb[e + 7];
            const unsigned short* p0 = xsrc + (size_t)c0 * 64;
            const unsigned short* p1 = xsrc + (size_t)c1 * 64;
            const unsigned short* p2 = xsrc + (size_t)c2 * 64;
            const unsigned short* p3 = xsrc + (size_t)c3 * 64;
            const unsigned short* p4 = xsrc + (size_t)c4 * 64;
            const unsigned short* p5 = xsrc + (size_t)c5 * 64;
            const unsigned short* p6 = xsrc + (size_t)c6 * 64;
            const unsigned short* p7 = xsrc + (size_t)c7 * 64;
            uint4 g00 = *(const uint4*)(p0 + s8);
            uint4 g01 = *(const uint4*)(p0 + 32 + s8);
            uint4 g10 = *(const uint4*)(p1 + s8);
            uint4 g11 = *(const uint4*)(p1 + 32 + s8);
            uint4 g20 = *(const uint4*)(p2 + s8);
            uint4 g21 = *(const uint4*)(p2 + 32 + s8);
            uint4 g30 = *(const uint4*)(p3 + s8);
            uint4 g31 = *(const uint4*)(p3 + 32 + s8);
            uint4 g40 = *(const uint4*)(p4 + s8);
            uint4 g41 = *(const uint4*)(p4 + 32 + s8);
            uint4 g50 = *(const uint4*)(p5 + s8);
            uint4 g51 = *(const uint4*)(p5 + 32 + s8);
            uint4 g60 = *(const uint4*)(p6 + s8);
            uint4 g61 = *(const uint4*)(p6 + 32 + s8);
            uint4 g70 = *(const uint4*)(p7 + s8);
            uint4 g71 = *(const uint4*)(p7 + 32 + s8);
            fma8(a0lo, a0hi, v0, g00);
            fma8(a1lo, a1hi, v0, g01);
            fma8(a0lo, a0hi, v1, g10);
            fma8(a1lo, a1hi, v1, g11);
            fma8(a0lo, a0hi, v2, g20);
            fma8(a1lo, a1hi, v2, g21);
            fma8(a0lo, a0hi, v3, g30);
            fma8(a1lo, a1hi, v3, g31);
            fma8(a0lo, a0hi, v4, g40);
            fma8(a1lo, a1hi, v4, g41);
            fma8(a0lo, a0hi, v5, g50);
            fma8(a1lo, a1hi, v5, g51);
            fma8(a0lo, a0hi, v6, g60);
            fma8(a1lo, a1hi, v6, g61);
            fma8(a0lo, a0hi, v7, g70);
            fma8(a1lo, a1hi, v7, g71);
        }
        if (e + 3 < pe) {
            int   c0 = cb[e];
            int   c1 = cb[e + 1];
            int   c2 = cb[e + 2];
            int   c3 = cb[e + 3];
            float v0 = vb[e];
            float v1 = vb[e + 1];
            float v2 = vb[e + 2];
            float v3 = vb[e + 3];
            const unsigned short* p0 = xsrc + (size_t)c0 * 64;
            const unsigned short* p1 = xsrc + (size_t)c1 * 64;
            const unsigned short* p2 = xsrc + (size_t)c2 * 64;
            const unsigned short* p3 = xsrc + (size_t)c3 * 64;
            uint4 g00 = *(const uint4*)(p0 + s8);
            uint4 g01 = *(const uint4*)(p0 + 32 + s8);
            uint4 g10 = *(const uint4*)(p1 + s8);
            uint4 g11 = *(const uint4*)(p1 + 32 + s8);
            uint4 g20 = *(const uint4*)(p2 + s8);
            uint4 g21 = *(const uint4*)(p2 + 32 + s8);
            uint4 g30 = *(const uint4*)(p3 + s8);
            uint4 g31 = *(const uint4*)(p3 + 32 + s8);
            fma8(a0lo, a0hi, v0, g00);
            fma8(a1lo, a1hi, v0, g01);
            fma8(a0lo, a0hi, v1, g10);
            fma8(a1lo, a1hi, v1, g11);
            fma8(a0lo, a0hi, v2, g20);
            fma8(a1lo, a1hi, v2, g21);
            fma8(a0lo, a0hi, v3, g30);
            fma8(a1lo, a1hi, v3, g31);
            e += 4;
        }
        if (e + 1 < pe) {
            int   c0 = cb[e];
            int   c1 = cb[e + 1];
            float v0 = vb[e];
            float v1 = vb[e + 1];
            const unsigned short* p0 = xsrc + (size_t)c0 * 64;
            const unsigned short* p1 = xsrc + (size_t)c1 * 64;
            uint4 g00 = *(const uint4*)(p0 + s8);
            uint4 g01 = *(const uint4*)(p0 + 32 + s8);
            uint4 g10 = *(const uint4*)(p1 + s8);
            uint4 g11 = *(const uint4*)(p1 + 32 + s8);
            fma8(a0lo, a0hi, v0, g00);
            fma8(a1lo, a1hi, v0, g01);
            fma8(a0lo, a0hi, v1, g10);
            fma8(a1lo, a1hi, v1, g11);
            e += 2;
        }
        if (e < pe) {
            int   c0 = cb[e];
            float v0 = vb[e];
            const unsigned short* p0 = xsrc + (size_t)c0 * 64;
            uint4 g00 = *(const uint4*)(p0 + s8);
            uint4 g01 = *(const uint4*)(p0 + 32 + s8);
            fma8(a0lo, a0hi, v0, g00);
            fma8(a1lo, a1hi, v0, g01);
        }
        short8 af0 = pack_af(a0lo, a0hi);   // A-frag, K-half 0 (k = quad*8+j)
        short8 af1 = pack_af(a1lo, a1hi);   // A-frag, K-half 1 (k = 32+quad*8+j)

        // ---- MFMA: D[16x64] += A[16x64] x W_k[64x64] (two 16x16x32 halves) ----
        const unsigned short* Wp = WTl + pk * 4096;
        short8 b00 = *(const short8*)(Wp + ( 0 + m) * 64 + s8);
        short8 b10 = *(const short8*)(Wp + (16 + m) * 64 + s8);
        short8 b20 = *(const short8*)(Wp + (32 + m) * 64 + s8);
        short8 b30 = *(const short8*)(Wp + (48 + m) * 64 + s8);
        d0 = __builtin_amdgcn_mfma_f32_16x16x32_bf16(af0, b00, d0, 0, 0, 0);
        d1 = __builtin_amdgcn_mfma_f32_16x16x32_bf16(af0, b10, d1, 0, 0, 0);
        d2 = __builtin_amdgcn_mfma_f32_16x16x32_bf16(af0, b20, d2, 0, 0, 0);
        d3 = __builtin_amdgcn_mfma_f32_16x16x32_bf16(af0, b30, d3, 0, 0, 0);
        short8 b01 = *(const short8*)(Wp + ( 0 + m) * 64 + 32 + s8);
        short8 b11 = *(const short8*)(Wp + (16 + m) * 64 + 32 + s8);
        short8 b21 = *(const short8*)(Wp + (32 + m) * 64 + 32 + s8);
        short8 b31 = *(const short8*)(Wp + (48 + m) * 64 + 32 + s8);
        d0 = __builtin_amdgcn_mfma_f32_16x16x32_bf16(af1, b01, d0, 0, 0, 0);
        d1 = __builtin_amdgcn_mfma_f32_16x16x32_bf16(af1, b11, d1, 0, 0, 0);
        d2 = __builtin_amdgcn_mfma_f32_16x16x32_bf16(af1, b21, d2, 0, 0, 0);
        d3 = __builtin_amdgcn_mfma_f32_16x16x32_bf16(af1, b31, d3, 0, 0, 0);
    }

    // ---- epilogue: C layout col=lane&15, row=quad*4+reg -> LDS -> coalesced ----
#pragma unroll
    for (int g = 0; g < 4; ++g) {
        C[(quad * 4 + g) * 65 +  0 + m] = d0[g];
        C[(quad * 4 + g) * 65 + 16 + m] = d1[g];
        C[(quad * 4 + g) * 65 + 32 + m] = d2[g];
        C[(quad * 4 + g) * 65 + 48 + m] = d3[g];
    }
    __builtin_amdgcn_s_waitcnt(0);   // drain lgkm before cross-lane LDS read (same wave)

    int row = lane >> 2;             // 0..15
    int qs  = lane & 3;              // 0..3 (16-channel segment)
    const float* Cr = C + row * 65 + qs * 16;
    float4 v0 = *(const float4*)(Cr + 0);
    float4 v1 = *(const float4*)(Cr + 4);
    float4 v2 = *(const float4*)(Cr + 8);
    float4 v3 = *(const float4*)(Cr + 12);
    if (layer == 2) {
        const uint4* res = (const uint4*)(xp.p[j] + (size_t)(r0 + row) * 64 + qs * 16);
        uint4 ra = res[0];
        uint4 rb = res[1];
        float4 o0 = bf16x4_to_f4(make_uint2(ra.x, ra.y));
        float4 o1 = bf16x4_to_f4(make_uint2(ra.z, ra.w));
        float4 o2 = bf16x4_to_f4(make_uint2(rb.x, rb.y));
        float4 o3 = bf16x4_to_f4(make_uint2(rb.z, rb.w));
        v0.x += o0.x; v0.y += o0.y; v0.z += o0.z; v0.w += o0.w;
        v1.x += o1.x; v1.y += o1.y; v1.z += o1.z; v1.w += o1.w;
        v2.x += o2.x; v2.y += o2.y; v2.z += o2.z; v2.w += o2.w;
        v3.x += o3.x; v3.y += o3.y; v3.z += o3.z; v3.w += o3.w;
    }
    v0.x = fmaxf(v0.x, 0.f); v0.y = fmaxf(v0.y, 0.f); v0.z = fmaxf(v0.z, 0.f); v0.w = fmaxf(v0.w, 0.f);
    v1.x = fmaxf(v1.x, 0.f); v1.y = fmaxf(v1.y, 0.f); v1.z = fmaxf(v1.z, 0.f); v1.w = fmaxf(v1.w, 0.f);
    v2.x = fmaxf(v2.x, 0.f); v2.y = fmaxf(v2.y, 0.f); v2.z = fmaxf(v2.z, 0.f); v2.w = fmaxf(v2.w, 0.f);
    v3.x = fmaxf(v3.x, 0.f); v3.y = fmaxf(v3.y, 0.f); v3.z = fmaxf(v3.z, 0.f); v3.w = fmaxf(v3.w, 0.f);
    uint2 s0 = f4_to_bf16x4(v0);
    uint2 s1 = f4_to_bf16x4(v1);
    uint2 s2 = f4_to_bf16x4(v2);
    uint2 s3 = f4_to_bf16x4(v3);
    uint4* dst = (uint4*)(xout + (size_t)(XOFF[j] + r0 + row) * 64 + qs * 16);
    dst[0] = make_uint4(s0.x, s0.y, s1.x, s1.y);
    dst[1] = make_uint4(s2.x, s2.y, s3.x, s3.y);
}

// ---------------------------------------------------------------------
// 3) pooling stage 1: per-(rank, block) partial sum/sumsq/max/min
//    uint4 loads (16B/lane, wave = 8 rows x 128B coalesced) + shfl reduce.
// ---------------------------------------------------------------------
__global__ __launch_bounds__(256) void k_pool1(const unsigned short* __restrict__ xs,
                                               double* __restrict__ psum,
                                               double* __restrict__ psq,
                                               float* __restrict__ pmax,
                                               float* __restrict__ pmin) {
    int rank = blockIdx.x >> 7;        // PB = 128
    int blk  = blockIdx.x & 127;
    int tid  = threadIdx.x;
    int rg   = tid >> 3;               // 0..31 row-group slot within block
    int cg   = tid & 7;                // channel group: channels cg*8 .. cg*8+7
    int wave = tid >> 6;
    int lane = tid & 63;

    int N = NRr[rank];
    const unsigned short* xb = xs + (size_t)XOFF[rank] * 64;

    double s[8], q[8];
    float mx[8], mn[8];
#pragma unroll
    for (int k = 0; k < 8; ++k) { s[k] = 0.0; q[k] = 0.0; mx[k] = -3.4e38f; mn[k] = 3.4e38f; }

    for (int r = blk * 32 + rg; r < N; r += PB * 32) {
        uint4 g = *(const uint4*)(xb + (size_t)r * 64 + cg * 8);
        float4 lo = bf16x4_to_f4(make_uint2(g.x, g.y));
        float4 hi = bf16x4_to_f4(make_uint2(g.z, g.w));
        float v[8] = {lo.x, lo.y, lo.z, lo.w, hi.x, hi.y, hi.z, hi.w};
#pragma unroll
        for (int k = 0; k < 8; ++k) {
            s[k] += v[k];
            q[k] += (double)v[k] * (double)v[k];
            mx[k] = fmaxf(mx[k], v[k]);
            mn[k] = fminf(mn[k], v[k]);
        }
    }

    // wave-level reduce across the 8 row-slots (lanes stride 8)
#pragma unroll
    for (int off = 8; off < 64; off <<= 1) {
#pragma unroll
        for (int k = 0; k < 8; ++k) {
            s[k] += __shfl_down(s[k], off, 64);
            q[k] += __shfl_down(q[k], off, 64);
            mx[k] = fmaxf(mx[k], __shfl_down(mx[k], off, 64));
            mn[k] = fminf(mn[k], __shfl_down(mn[k], off, 64));
        }
    }

    // cross-wave merge: lanes 0..7 of each wave hold channels lane*8+k
    __shared__ double ws_s[4][64], ws_q[4][64];
    __shared__ float  ws_mx[4][64], ws_mn[4][64];
    if (lane < 8) {
#pragma unroll
        for (int k = 0; k < 8; ++k) {
            ws_s[wave][lane * 8 + k]  = s[k];
            ws_q[wave][lane * 8 + k]  = q[k];
            ws_mx[wave][lane * 8 + k] = mx[k];
            ws_mn[wave][lane * 8 + k] = mn[k];
        }
    }
    __syncthreads();
    if (tid < 64) {
        double fs = ws_s[0][tid], fq = ws_q[0][tid];
        float fmx = ws_mx[0][tid], fmn = ws_mn[0][tid];
#pragma unroll
        for (int w = 1; w < 4; ++w) {
            fs += ws_s[w][tid]; fq += ws_q[w][tid];
            fmx = fmaxf(fmx, ws_mx[w][tid]); fmn = fminf(fmn, ws_mn[w][tid]);
        }
        int idx = (rank * PB + blk) * 64 + tid;
        psum[idx] = fs; psq[idx] = fq; pmax[idx] = fmx; pmin[idx] = fmn;
    }
}

// ---------------------------------------------------------------------
// 4) fc1 with inlined pool stage 2: each block recomputes sp[1284] into LDS
//    (bit-identical per-element order to the old k_pool2), then GEMV.
// ---------------------------------------------------------------------
__global__ __launch_bounds__(256) void k_fc1(const double* __restrict__ psum,
                                             const double* __restrict__ psq,
                                             const float* __restrict__ pmax,
                                             const float* __restrict__ pmin,
                                             const float* __restrict__ gf,
                                             const float* __restrict__ w1,
                                             const float* __restrict__ b1,
                                             float* __restrict__ h1) {
    __shared__ float sp[1284];
    __shared__ float red[16][17];
    int tid = threadIdx.x;

    // phase 1: pooled features (idx = rank*256 + group*64 + c)
    for (int idx = tid; idx < 1284; idx += 256) {
        if (idx < 1280) {
            int rank  = idx >> 8;
            int within = idx & 255;
            int group = within >> 6;
            int c     = within & 63;
            if (group < 2) {
                double s = 0.0, q = 0.0;
                for (int bb = 0; bb < PB; ++bb) {
                    int pidx = (rank * PB + bb) * 64 + c;
                    s += psum[pidx]; q += psq[pidx];
                }
                double N = (double)NRr[rank];
                double mean = s / N;
                if (group == 0) {
                    sp[idx] = (float)mean;
                } else {
                    double var = q / N - mean * mean;
                    if (var < 0.0) var = 0.0;
                    double sd = sqrt(var == 0.0 ? 1e-6 : var);
                    sp[idx] = (float)sd;
                }
            } else {
                float mx = -3.4e38f, mn = 3.4e38f;
                for (int bb = 0; bb < PB; ++bb) {
                    int pidx = (rank * PB + bb) * 64 + c;
                    mx = fmaxf(mx, pmax[pidx]); mn = fminf(mn, pmin[pidx]);
                }
                sp[idx] = (group == 2) ? mx : mn;
            }
        } else {
            sp[idx] = gf[idx - 1280];
        }
    }
    __syncthreads();

    // phase 2: GEMV 16 outputs per block, 16-way k-split
    int oi = tid & 15;
    int ks = tid >> 4;
    int o = (blockIdx.x << 4) | oi;
    float a = 0.f;
    for (int k = ks; k < 1284; k += 16) a += sp[k] * w1[(size_t)k * 512 + o];
    red[ks][oi] = a;
    __syncthreads();
    if (tid < 16) {
        float s = 0.f;
#pragma unroll
        for (int t = 0; t < 16; ++t) s += red[t][tid];
        int oo = (blockIdx.x << 4) | tid;
        h1[oo] = fmaxf(s + b1[oo], 0.f);
    }
}

// ---------------------------------------------------------------------
// 5) merged tail: fc2 (8 passes of the old 16-out x 16-ksplit pattern,
//    bit-identical) + fc3 + fc4 + output transform. One 256-thread block.
// ---------------------------------------------------------------------
__global__ __launch_bounds__(256) void k_tail2(const float* __restrict__ h1,
                                               const float* __restrict__ w2,
                                               const float* __restrict__ b2,
                                               const float* __restrict__ w3,
                                               const float* __restrict__ b3,
                                               const float* __restrict__ w4,
                                               const float* __restrict__ b4,
                                               float* __restrict__ out) {
    __shared__ float red[16][17];
    __shared__ float h2[128];
    __shared__ float h3[64];
    int tid = threadIdx.x;
    int oi = tid & 15;
    int ks = tid >> 4;

    // fc2: replicate old k_fc2 blocks as 8 sequential passes
    for (int pass = 0; pass < 8; ++pass) {
        int o = (pass << 4) | oi;
        float a = 0.f;
        for (int k = ks; k < 512; k += 16) a += h1[k] * w2[(size_t)k * 128 + o];
        red[ks][oi] = a;
        __syncthreads();
        if (tid < 16) {
            float s = 0.f;
#pragma unroll
            for (int t = 0; t < 16; ++t) s += red[t][tid];
            int oo = (pass << 4) | tid;
            h2[oo] = fmaxf(s + b2[oo], 0.f);
        }
        __syncthreads();
    }

    // fc3
    if (tid < 64) {
        float a = 0.f;
        for (int k = 0; k < 128; ++k) a += h2[k] * w3[k * 64 + tid];
        h3[tid] = fmaxf(a + b3[tid], 0.f);
    }
    __syncthreads();

    // fc4 + output transform
    if (tid < 2) {
        float s = 0.f;
#pragma unroll
        for (int k = 0; k < 64; ++k) s += h3[k] * w4[k * 2 + tid];
        s += b4[tid];
        if (tid == 1) s = s * s;
        out[tid] = s;
    }
}

// ---------------------------------------------------------------------
extern "C" void kernel_launch(void* const* d_in, const int* in_sizes, int n_in,
                              void* d_out, int out_size, void* d_ws, size_t ws_size,
                              hipStream_t stream) {
    if (ws_size < WS_NEEDED) {
        hipLaunchKernelGGL(k_diag, dim3(1), dim3(1), 0, stream,
                           (float*)d_out, (float)(ws_size >> 20));
        return;
    }

    const float* x0   = (const float*)d_in[0];
    const float* x1   = (const float*)d_in[1];
    const float* x2   = (const float*)d_in[2];
    const float* x3   = (const float*)d_in[3];
    const float* x4   = (const float*)d_in[4];
    const int*   rows = (const int*)d_in[5];
    const int*   cols = (const int*)d_in[6];
    const float* vals = (const float*)d_in[7];
    const float* gf   = (const float*)d_in[8];
    const float* Wh   = (const float*)d_in[9];
    const float* w1   = (const float*)d_in[10];
    const float* b1   = (const float*)d_in[11];
    const float* w2   = (const float*)d_in[12];
    const float* b2   = (const float*)d_in[13];
    const float* w3   = (const float*)d_in[14];
    const float* b3   = (const float*)d_in[15];
    const float* w4   = (const float*)d_in[16];
    const float* b4   = (const float*)d_in[17];

    char* ws = (char*)d_ws;
    unsigned short* b16in = (unsigned short*)(ws + WS_B16IN);
    unsigned short* b16x  = (unsigned short*)(ws + WS_B16X);
    unsigned short* b16y  = (unsigned short*)(ws + WS_B16Y);
    int*    rptr   = (int*)(ws + WS_PTR);
    unsigned short* WT = (unsigned short*)(ws + WS_WT);
    double* psum   = (double*)(ws + WS_PSUM);
    double* psq    = (double*)(ws + WS_PSQ);
    float*  pmax   = (float*)(ws + WS_PMAX);
    float*  pmin   = (float*)(ws + WS_PMIN);
    float*  h1     = (float*)(ws + WS_H1);

    XP xp_in; xp_in.p[0] = x0; xp_in.p[1] = x1; xp_in.p[2] = x2; xp_in.p[3] = x3; xp_in.p[4] = x4;
    hipLaunchKernelGGL(k_prep, dim3(PREP_BLOCKS), dim3(256), 0, stream,
                       xp_in, b16in, Wh, WT, rows, rptr);

    XPB xb_in, xb_x, xb_y;
    for (int i = 0; i < 5; ++i) {
        xb_in.p[i] = b16in + (size_t)XOFF[i] * 64;
        xb_x.p[i]  = b16x  + (size_t)XOFF[i] * 64;
        xb_y.p[i]  = b16y  + (size_t)XOFF[i] * 64;
    }

    // layer 0: b16in -> b16x ; layer 1: b16x -> b16y ; layer 2: b16y -> b16x (+residual)
    hipLaunchKernelGGL(k_fused, dim3(FUSED_BLOCKS), dim3(64), 0, stream,
                       xb_in, cols, vals, rptr, WT, b16x, 0);
    hipLaunchKernelGGL(k_fused, dim3(FUSED_BLOCKS), dim3(64), 0, stream,
                       xb_x, cols, vals, rptr, WT, b16y, 1);
    hipLaunchKernelGGL(k_fused, dim3(FUSED_BLOCKS), dim3(64), 0, stream,
                       xb_y, cols, vals, rptr, WT, b16x, 2);

    hipLaunchKernelGGL(k_pool1, dim3(5 * PB), dim3(256), 0, stream, b16x, psum, psq, pmax, pmin);
    hipLaunchKernelGGL(k_fc1, dim3(32), dim3(256), 0, stream, psum, psq, pmax, pmin, gf,
                       w1, b1, h1);
    hipLaunchKernelGGL(k_tail2, dim3(1), dim3(256), 0, stream, h1,
                       w2, b2, w3, b3, w4, b4, (float*)d_out);
}

// Round 9
// 846.209 us; speedup vs baseline: 1.0875x; 1.0875x over previous
//
#include <hip/hip_runtime.h>
#include <cstdint>
#include <cstddef>

// =====================================================================
// Network_28862180229296: 3-layer heterogeneous message passing + pooling + MLP
//
// Transposed formulation: hs_j = sum_k (A_k x_i) @ W_k   (segment-sum is linear)
//
// R17 structure (consolidation):
//  - k_fused: EXACT R12 body — 4-edge batch, launch_bounds(64,4), 60 VGPR,
//    186.5us/dispatch proven. R13(8e cap128)=spill, R15(2-stage)=84VGPR/207,
//    R16(8e uncapped)=84VGPR/207 -> compiler refuses >8-deep; structure is
//    at its scheduling optimum (~112 outstanding loads/CU, MSHR-class cap).
//  - k_pool2 PARALLELIZED: 5 blocks x 256 thr (64ch x 4 chunks of 32
//    partials), LDS combine in chunk order. Serial depth 128 -> 32.
//  - k_tail2 kept from R16 (fc2 as 8 bit-identical 16-out passes + fc3+fc4).
//  - k_prep merged cvt/cvtw/ptr; k_pool1 PB=128 uint4+shfl (R12).
// =====================================================================

namespace {

constexpr int NRr[5]  = {50000, 100000, 100000, 40000, 20000};
constexpr int PI[15]  = {0,1,2,3,4,0,0,0,0,1,1,1,2,2,3};
constexpr long long EOFF[15] = {0,400000,1200000,2000000,2320000,2480000,3280000,4080000,4400000,4560000,5360000,5680000,5840000,6160000,6320000};
constexpr int EK[15]  = {400000,800000,800000,320000,160000,800000,800000,320000,160000,800000,320000,160000,320000,160000,160000};
constexpr int POFF[15] = {0,50001,150002,250003,290004,310005,410006,510007,550008,570009,670010,710011,730012,770013,790014};
constexpr int PTR_TOT  = 810015;
constexpr int XOFF[5]  = {0,50000,150000,250000,290000};
constexpr int XROWS    = 310000;
constexpr int NPJ[5]    = {1,2,3,4,5};
constexpr int POJ[5][5] = {{0,0,0,0,0},{1,5,0,0,0},{2,6,9,0,0},{3,7,10,12,0},{4,8,11,13,14}};
// 16-row tiles, heavy-first (rank 4: 40 e/row ... rank 0: 8 e/row)
constexpr int TCUM[6]  = {0,1250,3750,10000,16250,19375};
constexpr int TRANK[5] = {4,3,2,1,0};
constexpr int FUSED_BLOCKS = 19375;

constexpr int PB = 128;   // pooling partial blocks per rank (640 blocks total)

// merged prologue grid sections
constexpr int CVT_BLOCKS  = (XROWS * 16) / 256;          // 19375 (exact)
constexpr int CVTW_BLOCKS = (3 * 15 * 4096) / 256;       // 720 (exact)
constexpr int PTR_BLOCKS  = (PTR_TOT + 255) / 256;       // 3165
constexpr int PREP_BLOCKS = CVT_BLOCKS + CVTW_BLOCKS + PTR_BLOCKS;

// ---- workspace layout (bytes) ----
constexpr size_t WS_B16IN = 0;                      // ushort[310000*64] = 39,680,000
constexpr size_t WS_B16X  = 39680000;
constexpr size_t WS_B16Y  = 79360000;
constexpr size_t WS_PTR   = 119040000;              // int[810015] = 3,240,060
constexpr size_t WS_WT    = 122280064;              // ushort[3*15*4096] = 368,640
constexpr size_t WS_PSUM  = 122648704;              // double[5*PB*64]
constexpr size_t WS_PSQ   = WS_PSUM + (size_t)5*PB*64*8;
constexpr size_t WS_PMAX  = WS_PSQ  + (size_t)5*PB*64*8;
constexpr size_t WS_PMIN  = WS_PMAX + (size_t)5*PB*64*4;
constexpr size_t WS_SP    = WS_PMIN + (size_t)5*PB*64*4;  // float[1284]
constexpr size_t WS_H1    = WS_SP + 5136;                 // float[512]
constexpr size_t WS_NEEDED = WS_H1 + 2048;

struct XP  { const float* p[5]; };
struct XPB { const unsigned short* p[5]; };

} // namespace

typedef __attribute__((ext_vector_type(8))) short short8;
typedef __attribute__((ext_vector_type(4))) float f32x4;

// ---------------------------------------------------------------------
// bf16 helpers (RNE)
// ---------------------------------------------------------------------
static __device__ __forceinline__ unsigned int rne_bf16(float x) {
    unsigned int b = __float_as_uint(x);
    return (b + 0x7fffu + ((b >> 16) & 1u)) >> 16;
}
static __device__ __forceinline__ float4 bf16x4_to_f4(uint2 u) {
    float4 f;
    f.x = __uint_as_float(u.x << 16);
    f.y = __uint_as_float(u.x & 0xffff0000u);
    f.z = __uint_as_float(u.y << 16);
    f.w = __uint_as_float(u.y & 0xffff0000u);
    return f;
}
static __device__ __forceinline__ uint2 f4_to_bf16x4(float4 v) {
    uint2 st;
    st.x = rne_bf16(v.x) | (rne_bf16(v.y) << 16);
    st.y = rne_bf16(v.z) | (rne_bf16(v.w) << 16);
    return st;
}
static __device__ __forceinline__ void fma4(float4& a, float s, const float4& b) {
    a.x += s * b.x; a.y += s * b.y; a.z += s * b.z; a.w += s * b.w;
}
static __device__ __forceinline__ void fma8(float4& alo, float4& ahi, float s, uint4 g) {
    fma4(alo, s, bf16x4_to_f4(make_uint2(g.x, g.y)));
    fma4(ahi, s, bf16x4_to_f4(make_uint2(g.z, g.w)));
}
static __device__ __forceinline__ short8 pack_af(float4 lo, float4 hi) {
    uint2 pa = f4_to_bf16x4(lo);
    uint2 pb = f4_to_bf16x4(hi);
    short8 af;
    ((unsigned int*)&af)[0] = pa.x;
    ((unsigned int*)&af)[1] = pa.y;
    ((unsigned int*)&af)[2] = pb.x;
    ((unsigned int*)&af)[3] = pb.y;
    return af;
}

// ---------------------------------------------------------------------
__global__ void k_diag(float* __restrict__ out, float v) {
    out[0] = v;
    out[1] = 0.f;
}

// ---------------------------------------------------------------------
// 0) merged prologue: [cvt inputs -> bf16 | transpose W -> bf16 | CSR row_ptr]
// ---------------------------------------------------------------------
__global__ __launch_bounds__(256) void k_prep(XP xin, unsigned short* __restrict__ b16,
                                              const float* __restrict__ Wh,
                                              unsigned short* __restrict__ WT,
                                              const int* __restrict__ rows,
                                              int* __restrict__ rptr) {
    int bx = blockIdx.x;
    if (bx < CVT_BLOCKS) {
        int q = bx * 256 + threadIdx.x;   // quad index (4 channels); grid exact
        int row = q >> 4;
        int rank = 0;
#pragma unroll
        for (int t = 1; t < 5; ++t) if (row >= XOFF[t]) rank = t;
        const float* src = xin.p[rank] + (size_t)(row - XOFF[rank]) * 64 + (q & 15) * 4;
        float4 v = *(const float4*)src;
        ((uint2*)b16)[q] = f4_to_bf16x4(v);
    } else if (bx < CVT_BLOCKS + CVTW_BLOCKS) {
        int tid = (bx - CVT_BLOCKS) * 256 + threadIdx.x;   // grid exact
        int lp = tid >> 12;
        int nk_ = tid & 4095;
        int n = nk_ >> 6;
        int k = nk_ & 63;
        float w = Wh[(size_t)lp * 4096 + k * 64 + n];
        WT[tid] = (unsigned short)rne_bf16(w);
    } else {
        int tid = (bx - CVT_BLOCKS - CVTW_BLOCKS) * 256 + threadIdx.x;
        if (tid >= PTR_TOT) return;
        int k = 0;
#pragma unroll
        for (int t = 1; t < 15; ++t) if (tid >= POFF[t]) k = t;
        int r = tid - POFF[k];
        const int* rb = rows + EOFF[k];
        int lo = 0, hi = EK[k];
        while (lo < hi) {
            int mid = (lo + hi) >> 1;
            if (rb[mid] < r) lo = mid + 1; else hi = mid;
        }
        rptr[tid] = lo;
    }
}

// ---------------------------------------------------------------------
// 2) fused aggregate (reg-direct bf16 gather) + MFMA GEMM + residual + relu
//    EXACT R12 body: one wave per 16-row tile, 4-edge batch, (64,4).
// ---------------------------------------------------------------------
__global__ __launch_bounds__(64, 4) void k_fused(XPB xp,
                                                 const int* __restrict__ cols,
                                                 const float* __restrict__ vals,
                                                 const int* __restrict__ rptr,
                                                 const unsigned short* __restrict__ WT,
                                                 unsigned short* __restrict__ xout,
                                                 int layer) {
    __shared__ float C[16 * 65];   // 4160 B, C-epilogue transpose only

    int b = blockIdx.x;
    int seg = 0;
#pragma unroll
    for (int t = 1; t < 5; ++t) if (b >= TCUM[t]) seg = t;
    int j  = TRANK[seg];
    int r0 = (b - TCUM[seg]) * 16;

    int lane = threadIdx.x;
    int m    = lane & 15;          // owned output row (A-frag m index / B-frag n index)
    int quad = lane >> 4;          // 0..3
    int s8   = quad * 8;           // channel-slice base (shorts) within a K-half

    f32x4 d0 = {0.f,0.f,0.f,0.f};
    f32x4 d1 = d0, d2 = d0, d3 = d0;

    const unsigned short* WTl = WT + (size_t)layer * 15 * 4096;
    int nk = NPJ[j];
    for (int kc = 0; kc < nk; ++kc) {
        int pk = POJ[j][kc];
        const unsigned short* __restrict__ xsrc = xp.p[PI[pk]];
        const int*   __restrict__ cb = cols + EOFF[pk];
        const float* __restrict__ vb = vals + EOFF[pk];
        const int*   __restrict__ rp = rptr + POFF[pk];

        // ---- gather this pair: 16 rows concurrently, 4-edge batch per row ----
        int ps = rp[r0 + m];
        int pe = rp[r0 + m + 1];
        float4 a0lo = make_float4(0.f,0.f,0.f,0.f), a0hi = a0lo;  // K-half 0
        float4 a1lo = a0lo, a1hi = a0lo;                          // K-half 1
        int e = ps;
        for (; e + 3 < pe; e += 4) {
            int   c0 = cb[e];
            int   c1 = cb[e + 1];
            int   c2 = cb[e + 2];
            int   c3 = cb[e + 3];
            float v0 = vb[e];
            float v1 = vb[e + 1];
            float v2 = vb[e + 2];
            float v3 = vb[e + 3];
            const unsigned short* p0 = xsrc + (size_t)c0 * 64;
            const unsigned short* p1 = xsrc + (size_t)c1 * 64;
            const unsigned short* p2 = xsrc + (size_t)c2 * 64;
            const unsigned short* p3 = xsrc + (size_t)c3 * 64;
            uint4 g00 = *(const uint4*)(p0 + s8);
            uint4 g01 = *(const uint4*)(p0 + 32 + s8);
            uint4 g10 = *(const uint4*)(p1 + s8);
            uint4 g11 = *(const uint4*)(p1 + 32 + s8);
            uint4 g20 = *(const uint4*)(p2 + s8);
            uint4 g21 = *(const uint4*)(p2 + 32 + s8);
            uint4 g30 = *(const uint4*)(p3 + s8);
            uint4 g31 = *(const uint4*)(p3 + 32 + s8);
            fma8(a0lo, a0hi, v0, g00);
            fma8(a1lo, a1hi, v0, g01);
            fma8(a0lo, a0hi, v1, g10);
            fma8(a1lo, a1hi, v1, g11);
            fma8(a0lo, a0hi, v2, g20);
            fma8(a1lo, a1hi, v2, g21);
            fma8(a0lo, a0hi, v3, g30);
            fma8(a1lo, a1hi, v3, g31);
        }
        if (e + 1 < pe) {
            int   c0 = cb[e];
            int   c1 = cb[e + 1];
            float v0 = vb[e];
            float v1 = vb[e + 1];
            const unsigned short* p0 = xsrc + (size_t)c0 * 64;
            const unsigned short* p1 = xsrc + (size_t)c1 * 64;
            uint4 g00 = *(const uint4*)(p0 + s8);
            uint4 g01 = *(const uint4*)(p0 + 32 + s8);
            uint4 g10 = *(const uint4*)(p1 + s8);
            uint4 g11 = *(const uint4*)(p1 + 32 + s8);
            fma8(a0lo, a0hi, v0, g00);
            fma8(a1lo, a1hi, v0, g01);
            fma8(a0lo, a0hi, v1, g10);
            fma8(a1lo, a1hi, v1, g11);
            e += 2;
        }
        if (e < pe) {
            int   c0 = cb[e];
            float v0 = vb[e];
            const unsigned short* p0 = xsrc + (size_t)c0 * 64;
            uint4 g00 = *(const uint4*)(p0 + s8);
            uint4 g01 = *(const uint4*)(p0 + 32 + s8);
            fma8(a0lo, a0hi, v0, g00);
            fma8(a1lo, a1hi, v0, g01);
        }
        short8 af0 = pack_af(a0lo, a0hi);   // A-frag, K-half 0 (k = quad*8+j)
        short8 af1 = pack_af(a1lo, a1hi);   // A-frag, K-half 1 (k = 32+quad*8+j)

        // ---- MFMA: D[16x64] += A[16x64] x W_k[64x64] (two 16x16x32 halves) ----
        const unsigned short* Wp = WTl + pk * 4096;
        short8 b00 = *(const short8*)(Wp + ( 0 + m) * 64 + s8);
        short8 b10 = *(const short8*)(Wp + (16 + m) * 64 + s8);
        short8 b20 = *(const short8*)(Wp + (32 + m) * 64 + s8);
        short8 b30 = *(const short8*)(Wp + (48 + m) * 64 + s8);
        d0 = __builtin_amdgcn_mfma_f32_16x16x32_bf16(af0, b00, d0, 0, 0, 0);
        d1 = __builtin_amdgcn_mfma_f32_16x16x32_bf16(af0, b10, d1, 0, 0, 0);
        d2 = __builtin_amdgcn_mfma_f32_16x16x32_bf16(af0, b20, d2, 0, 0, 0);
        d3 = __builtin_amdgcn_mfma_f32_16x16x32_bf16(af0, b30, d3, 0, 0, 0);
        short8 b01 = *(const short8*)(Wp + ( 0 + m) * 64 + 32 + s8);
        short8 b11 = *(const short8*)(Wp + (16 + m) * 64 + 32 + s8);
        short8 b21 = *(const short8*)(Wp + (32 + m) * 64 + 32 + s8);
        short8 b31 = *(const short8*)(Wp + (48 + m) * 64 + 32 + s8);
        d0 = __builtin_amdgcn_mfma_f32_16x16x32_bf16(af1, b01, d0, 0, 0, 0);
        d1 = __builtin_amdgcn_mfma_f32_16x16x32_bf16(af1, b11, d1, 0, 0, 0);
        d2 = __builtin_amdgcn_mfma_f32_16x16x32_bf16(af1, b21, d2, 0, 0, 0);
        d3 = __builtin_amdgcn_mfma_f32_16x16x32_bf16(af1, b31, d3, 0, 0, 0);
    }

    // ---- epilogue: C layout col=lane&15, row=quad*4+reg -> LDS -> coalesced ----
#pragma unroll
    for (int g = 0; g < 4; ++g) {
        C[(quad * 4 + g) * 65 +  0 + m] = d0[g];
        C[(quad * 4 + g) * 65 + 16 + m] = d1[g];
        C[(quad * 4 + g) * 65 + 32 + m] = d2[g];
        C[(quad * 4 + g) * 65 + 48 + m] = d3[g];
    }
    __builtin_amdgcn_s_waitcnt(0);   // drain lgkm before cross-lane LDS read (same wave)

    int row = lane >> 2;             // 0..15
    int qs  = lane & 3;              // 0..3 (16-channel segment)
    const float* Cr = C + row * 65 + qs * 16;
    float4 v0 = *(const float4*)(Cr + 0);
    float4 v1 = *(const float4*)(Cr + 4);
    float4 v2 = *(const float4*)(Cr + 8);
    float4 v3 = *(const float4*)(Cr + 12);
    if (layer == 2) {
        const uint4* res = (const uint4*)(xp.p[j] + (size_t)(r0 + row) * 64 + qs * 16);
        uint4 ra = res[0];
        uint4 rb = res[1];
        float4 o0 = bf16x4_to_f4(make_uint2(ra.x, ra.y));
        float4 o1 = bf16x4_to_f4(make_uint2(ra.z, ra.w));
        float4 o2 = bf16x4_to_f4(make_uint2(rb.x, rb.y));
        float4 o3 = bf16x4_to_f4(make_uint2(rb.z, rb.w));
        v0.x += o0.x; v0.y += o0.y; v0.z += o0.z; v0.w += o0.w;
        v1.x += o1.x; v1.y += o1.y; v1.z += o1.z; v1.w += o1.w;
        v2.x += o2.x; v2.y += o2.y; v2.z += o2.z; v2.w += o2.w;
        v3.x += o3.x; v3.y += o3.y; v3.z += o3.z; v3.w += o3.w;
    }
    v0.x = fmaxf(v0.x, 0.f); v0.y = fmaxf(v0.y, 0.f); v0.z = fmaxf(v0.z, 0.f); v0.w = fmaxf(v0.w, 0.f);
    v1.x = fmaxf(v1.x, 0.f); v1.y = fmaxf(v1.y, 0.f); v1.z = fmaxf(v1.z, 0.f); v1.w = fmaxf(v1.w, 0.f);
    v2.x = fmaxf(v2.x, 0.f); v2.y = fmaxf(v2.y, 0.f); v2.z = fmaxf(v2.z, 0.f); v2.w = fmaxf(v2.w, 0.f);
    v3.x = fmaxf(v3.x, 0.f); v3.y = fmaxf(v3.y, 0.f); v3.z = fmaxf(v3.z, 0.f); v3.w = fmaxf(v3.w, 0.f);
    uint2 s0 = f4_to_bf16x4(v0);
    uint2 s1 = f4_to_bf16x4(v1);
    uint2 s2 = f4_to_bf16x4(v2);
    uint2 s3 = f4_to_bf16x4(v3);
    uint4* dst = (uint4*)(xout + (size_t)(XOFF[j] + r0 + row) * 64 + qs * 16);
    dst[0] = make_uint4(s0.x, s0.y, s1.x, s1.y);
    dst[1] = make_uint4(s2.x, s2.y, s3.x, s3.y);
}

// ---------------------------------------------------------------------
// 3) pooling stage 1: per-(rank, block) partial sum/sumsq/max/min
//    uint4 loads (16B/lane, wave = 8 rows x 128B coalesced) + shfl reduce.
// ---------------------------------------------------------------------
__global__ __launch_bounds__(256) void k_pool1(const unsigned short* __restrict__ xs,
                                               double* __restrict__ psum,
                                               double* __restrict__ psq,
                                               float* __restrict__ pmax,
                                               float* __restrict__ pmin) {
    int rank = blockIdx.x >> 7;        // PB = 128
    int blk  = blockIdx.x & 127;
    int tid  = threadIdx.x;
    int rg   = tid >> 3;               // 0..31 row-group slot within block
    int cg   = tid & 7;                // channel group: channels cg*8 .. cg*8+7
    int wave = tid >> 6;
    int lane = tid & 63;

    int N = NRr[rank];
    const unsigned short* xb = xs + (size_t)XOFF[rank] * 64;

    double s[8], q[8];
    float mx[8], mn[8];
#pragma unroll
    for (int k = 0; k < 8; ++k) { s[k] = 0.0; q[k] = 0.0; mx[k] = -3.4e38f; mn[k] = 3.4e38f; }

    for (int r = blk * 32 + rg; r < N; r += PB * 32) {
        uint4 g = *(const uint4*)(xb + (size_t)r * 64 + cg * 8);
        float4 lo = bf16x4_to_f4(make_uint2(g.x, g.y));
        float4 hi = bf16x4_to_f4(make_uint2(g.z, g.w));
        float v[8] = {lo.x, lo.y, lo.z, lo.w, hi.x, hi.y, hi.z, hi.w};
#pragma unroll
        for (int k = 0; k < 8; ++k) {
            s[k] += v[k];
            q[k] += (double)v[k] * (double)v[k];
            mx[k] = fmaxf(mx[k], v[k]);
            mn[k] = fminf(mn[k], v[k]);
        }
    }

    // wave-level reduce across the 8 row-slots (lanes stride 8)
#pragma unroll
    for (int off = 8; off < 64; off <<= 1) {
#pragma unroll
        for (int k = 0; k < 8; ++k) {
            s[k] += __shfl_down(s[k], off, 64);
            q[k] += __shfl_down(q[k], off, 64);
            mx[k] = fmaxf(mx[k], __shfl_down(mx[k], off, 64));
            mn[k] = fminf(mn[k], __shfl_down(mn[k], off, 64));
        }
    }

    // cross-wave merge: lanes 0..7 of each wave hold channels lane*8+k
    __shared__ double ws_s[4][64], ws_q[4][64];
    __shared__ float  ws_mx[4][64], ws_mn[4][64];
    if (lane < 8) {
#pragma unroll
        for (int k = 0; k < 8; ++k) {
            ws_s[wave][lane * 8 + k]  = s[k];
            ws_q[wave][lane * 8 + k]  = q[k];
            ws_mx[wave][lane * 8 + k] = mx[k];
            ws_mn[wave][lane * 8 + k] = mn[k];
        }
    }
    __syncthreads();
    if (tid < 64) {
        double fs = ws_s[0][tid], fq = ws_q[0][tid];
        float fmx = ws_mx[0][tid], fmn = ws_mn[0][tid];
#pragma unroll
        for (int w = 1; w < 4; ++w) {
            fs += ws_s[w][tid]; fq += ws_q[w][tid];
            fmx = fmaxf(fmx, ws_mx[w][tid]); fmn = fminf(fmn, ws_mn[w][tid]);
        }
        int idx = (rank * PB + blk) * 64 + tid;
        psum[idx] = fs; psq[idx] = fq; pmax[idx] = fmx; pmin[idx] = fmn;
    }
}

// ---------------------------------------------------------------------
// 4) pooling stage 2 (PARALLELIZED): 5 blocks (one per rank) x 256 threads.
//    Thread (chunk, c) reduces 32 partials; LDS combine in chunk order.
// ---------------------------------------------------------------------
__global__ __launch_bounds__(256) void k_pool2(const double* __restrict__ psum,
                                               const double* __restrict__ psq,
                                               const float* __restrict__ pmax,
                                               const float* __restrict__ pmin,
                                               const float* __restrict__ gf,
                                               float* __restrict__ sp) {
    __shared__ double cs[4][64], cq[4][64];
    __shared__ float  cmx[4][64], cmn[4][64];
    int rank  = blockIdx.x;
    int tid   = threadIdx.x;
    int chunk = tid >> 6;              // 0..3
    int c     = tid & 63;

    double s = 0.0, q = 0.0;
    float mx = -3.4e38f, mn = 3.4e38f;
    for (int b = chunk * 32; b < chunk * 32 + 32; ++b) {
        int idx = (rank * PB + b) * 64 + c;
        s += psum[idx]; q += psq[idx];
        mx = fmaxf(mx, pmax[idx]); mn = fminf(mn, pmin[idx]);
    }
    cs[chunk][c] = s; cq[chunk][c] = q; cmx[chunk][c] = mx; cmn[chunk][c] = mn;
    __syncthreads();
    if (chunk == 0) {
#pragma unroll
        for (int t = 1; t < 4; ++t) {
            s += cs[t][c]; q += cq[t][c];
            mx = fmaxf(mx, cmx[t][c]); mn = fminf(mn, cmn[t][c]);
        }
        double N = (double)NRr[rank];
        double mean = s / N;
        double var  = q / N - mean * mean;
        if (var < 0.0) var = 0.0;
        double sd = sqrt(var == 0.0 ? 1e-6 : var);
        sp[rank * 256 + c]       = (float)mean;
        sp[rank * 256 + 64 + c]  = (float)sd;
        sp[rank * 256 + 128 + c] = mx;
        sp[rank * 256 + 192 + c] = mn;
        if (rank == 0 && c < 4) sp[1280 + c] = gf[c];
    }
}

// ---------------------------------------------------------------------
// 5) fc1: [1,1284] @ [1284,512]. 32 blocks x 16 outputs, 16-way k-split.
// ---------------------------------------------------------------------
__global__ __launch_bounds__(256) void k_fc1(const float* __restrict__ sp,
                                             const float* __restrict__ w1,
                                             const float* __restrict__ b1,
                                             float* __restrict__ h1) {
    __shared__ float red[16][17];
    int tid = threadIdx.x;
    int oi = tid & 15;
    int ks = tid >> 4;
    int o = (blockIdx.x << 4) | oi;
    float a = 0.f;
    for (int k = ks; k < 1284; k += 16) a += sp[k] * w1[(size_t)k * 512 + o];
    red[ks][oi] = a;
    __syncthreads();
    if (tid < 16) {
        float s = 0.f;
#pragma unroll
        for (int t = 0; t < 16; ++t) s += red[t][tid];
        int oo = (blockIdx.x << 4) | tid;
        h1[oo] = fmaxf(s + b1[oo], 0.f);
    }
}

// ---------------------------------------------------------------------
// 6) merged tail: fc2 (8 passes of the old 16-out x 16-ksplit pattern,
//    bit-identical) + fc3 + fc4 + output transform. One 256-thread block.
// ---------------------------------------------------------------------
__global__ __launch_bounds__(256) void k_tail2(const float* __restrict__ h1,
                                               const float* __restrict__ w2,
                                               const float* __restrict__ b2,
                                               const float* __restrict__ w3,
                                               const float* __restrict__ b3,
                                               const float* __restrict__ w4,
                                               const float* __restrict__ b4,
                                               float* __restrict__ out) {
    __shared__ float red[16][17];
    __shared__ float h2[128];
    __shared__ float h3[64];
    int tid = threadIdx.x;
    int oi = tid & 15;
    int ks = tid >> 4;

    // fc2: replicate old k_fc2 blocks as 8 sequential passes
    for (int pass = 0; pass < 8; ++pass) {
        int o = (pass << 4) | oi;
        float a = 0.f;
        for (int k = ks; k < 512; k += 16) a += h1[k] * w2[(size_t)k * 128 + o];
        red[ks][oi] = a;
        __syncthreads();
        if (tid < 16) {
            float s = 0.f;
#pragma unroll
            for (int t = 0; t < 16; ++t) s += red[t][tid];
            int oo = (pass << 4) | tid;
            h2[oo] = fmaxf(s + b2[oo], 0.f);
        }
        __syncthreads();
    }

    // fc3
    if (tid < 64) {
        float a = 0.f;
        for (int k = 0; k < 128; ++k) a += h2[k] * w3[k * 64 + tid];
        h3[tid] = fmaxf(a + b3[tid], 0.f);
    }
    __syncthreads();

    // fc4 + output transform
    if (tid < 2) {
        float s = 0.f;
#pragma unroll
        for (int k = 0; k < 64; ++k) s += h3[k] * w4[k * 2 + tid];
        s += b4[tid];
        if (tid == 1) s = s * s;
        out[tid] = s;
    }
}

// ---------------------------------------------------------------------
extern "C" void kernel_launch(void* const* d_in, const int* in_sizes, int n_in,
                              void* d_out, int out_size, void* d_ws, size_t ws_size,
                              hipStream_t stream) {
    if (ws_size < WS_NEEDED) {
        hipLaunchKernelGGL(k_diag, dim3(1), dim3(1), 0, stream,
                           (float*)d_out, (float)(ws_size >> 20));
        return;
    }

    const float* x0   = (const float*)d_in[0];
    const float* x1   = (const float*)d_in[1];
    const float* x2   = (const float*)d_in[2];
    const float* x3   = (const float*)d_in[3];
    const float* x4   = (const float*)d_in[4];
    const int*   rows = (const int*)d_in[5];
    const int*   cols = (const int*)d_in[6];
    const float* vals = (const float*)d_in[7];
    const float* gf   = (const float*)d_in[8];
    const float* Wh   = (const float*)d_in[9];
    const float* w1   = (const float*)d_in[10];
    const float* b1   = (const float*)d_in[11];
    const float* w2   = (const float*)d_in[12];
    const float* b2   = (const float*)d_in[13];
    const float* w3   = (const float*)d_in[14];
    const float* b3   = (const float*)d_in[15];
    const float* w4   = (const float*)d_in[16];
    const float* b4   = (const float*)d_in[17];

    char* ws = (char*)d_ws;
    unsigned short* b16in = (unsigned short*)(ws + WS_B16IN);
    unsigned short* b16x  = (unsigned short*)(ws + WS_B16X);
    unsigned short* b16y  = (unsigned short*)(ws + WS_B16Y);
    int*    rptr   = (int*)(ws + WS_PTR);
    unsigned short* WT = (unsigned short*)(ws + WS_WT);
    double* psum   = (double*)(ws + WS_PSUM);
    double* psq    = (double*)(ws + WS_PSQ);
    float*  pmax   = (float*)(ws + WS_PMAX);
    float*  pmin   = (float*)(ws + WS_PMIN);
    float*  sp     = (float*)(ws + WS_SP);
    float*  h1     = (float*)(ws + WS_H1);

    XP xp_in; xp_in.p[0] = x0; xp_in.p[1] = x1; xp_in.p[2] = x2; xp_in.p[3] = x3; xp_in.p[4] = x4;
    hipLaunchKernelGGL(k_prep, dim3(PREP_BLOCKS), dim3(256), 0, stream,
                       xp_in, b16in, Wh, WT, rows, rptr);

    XPB xb_in, xb_x, xb_y;
    for (int i = 0; i < 5; ++i) {
        xb_in.p[i] = b16in + (size_t)XOFF[i] * 64;
        xb_x.p[i]  = b16x  + (size_t)XOFF[i] * 64;
        xb_y.p[i]  = b16y  + (size_t)XOFF[i] * 64;
    }

    // layer 0: b16in -> b16x ; layer 1: b16x -> b16y ; layer 2: b16y -> b16x (+residual)
    hipLaunchKernelGGL(k_fused, dim3(FUSED_BLOCKS), dim3(64), 0, stream,
                       xb_in, cols, vals, rptr, WT, b16x, 0);
    hipLaunchKernelGGL(k_fused, dim3(FUSED_BLOCKS), dim3(64), 0, stream,
                       xb_x, cols, vals, rptr, WT, b16y, 1);
    hipLaunchKernelGGL(k_fused, dim3(FUSED_BLOCKS), dim3(64), 0, stream,
                       xb_y, cols, vals, rptr, WT, b16x, 2);

    hipLaunchKernelGGL(k_pool1, dim3(5 * PB), dim3(256), 0, stream, b16x, psum, psq, pmax, pmin);
    hipLaunchKernelGGL(k_pool2, dim3(5), dim3(256), 0, stream, psum, psq, pmax, pmin, gf, sp);
    hipLaunchKernelGGL(k_fc1, dim3(32), dim3(256), 0, stream, sp, w1, b1, h1);
    hipLaunchKernelGGL(k_tail2, dim3(1), dim3(256), 0, stream, h1,
                       w2, b2, w3, b3, w4, b4, (float*)d_out);
}

// Round 10
// 789.504 us; speedup vs baseline: 1.1656x; 1.0718x over previous
//
#include <hip/hip_runtime.h>
#include <cstdint>
#include <cstddef>

// =====================================================================
// Network_28862180229296: 3-layer heterogeneous message passing + pooling + MLP
//
// Transposed formulation: hs_j = sum_k (A_k x_i) @ W_k   (segment-sum is linear)
//
// R18 structure (all-proven consolidation):
//  - k_fused: R12 body — 4-edge batch, launch_bounds(64,4), 60 VGPR,
//    186.6us/dispatch (verified R12, R17). Structure plateaued: deeper
//    batches spill (R13) or re-serialize (R15/R16); more waves don't help
//    (R10/R14) -> latency/MSHR-bound at ~112 outstanding loads/CU.
//  - tail: pool2 5-block parallel (R17-verified) + fc1 32-blk + fc2 8-BLK
//    PARALLEL + rest (R12-proven). R16/R17 lesson: single-CU serialization
//    of latency-bound passes costs ~60-75us to save one ~20us launch gap.
//  - k_prep merged cvt/cvtw/ptr; k_pool1 PB=128 uint4+shfl (R12).
// =====================================================================

namespace {

constexpr int NRr[5]  = {50000, 100000, 100000, 40000, 20000};
constexpr int PI[15]  = {0,1,2,3,4,0,0,0,0,1,1,1,2,2,3};
constexpr long long EOFF[15] = {0,400000,1200000,2000000,2320000,2480000,3280000,4080000,4400000,4560000,5360000,5680000,5840000,6160000,6320000};
constexpr int EK[15]  = {400000,800000,800000,320000,160000,800000,800000,320000,160000,800000,320000,160000,320000,160000,160000};
constexpr int POFF[15] = {0,50001,150002,250003,290004,310005,410006,510007,550008,570009,670010,710011,730012,770013,790014};
constexpr int PTR_TOT  = 810015;
constexpr int XOFF[5]  = {0,50000,150000,250000,290000};
constexpr int XROWS    = 310000;
constexpr int NPJ[5]    = {1,2,3,4,5};
constexpr int POJ[5][5] = {{0,0,0,0,0},{1,5,0,0,0},{2,6,9,0,0},{3,7,10,12,0},{4,8,11,13,14}};
// 16-row tiles, heavy-first (rank 4: 40 e/row ... rank 0: 8 e/row)
constexpr int TCUM[6]  = {0,1250,3750,10000,16250,19375};
constexpr int TRANK[5] = {4,3,2,1,0};
constexpr int FUSED_BLOCKS = 19375;

constexpr int PB = 128;   // pooling partial blocks per rank (640 blocks total)

// merged prologue grid sections
constexpr int CVT_BLOCKS  = (XROWS * 16) / 256;          // 19375 (exact)
constexpr int CVTW_BLOCKS = (3 * 15 * 4096) / 256;       // 720 (exact)
constexpr int PTR_BLOCKS  = (PTR_TOT + 255) / 256;       // 3165
constexpr int PREP_BLOCKS = CVT_BLOCKS + CVTW_BLOCKS + PTR_BLOCKS;

// ---- workspace layout (bytes) ----
constexpr size_t WS_B16IN = 0;                      // ushort[310000*64] = 39,680,000
constexpr size_t WS_B16X  = 39680000;
constexpr size_t WS_B16Y  = 79360000;
constexpr size_t WS_PTR   = 119040000;              // int[810015] = 3,240,060
constexpr size_t WS_WT    = 122280064;              // ushort[3*15*4096] = 368,640
constexpr size_t WS_PSUM  = 122648704;              // double[5*PB*64]
constexpr size_t WS_PSQ   = WS_PSUM + (size_t)5*PB*64*8;
constexpr size_t WS_PMAX  = WS_PSQ  + (size_t)5*PB*64*8;
constexpr size_t WS_PMIN  = WS_PMAX + (size_t)5*PB*64*4;
constexpr size_t WS_SP    = WS_PMIN + (size_t)5*PB*64*4;  // float[1284]
constexpr size_t WS_H1    = WS_SP + 5136;                 // float[512]
constexpr size_t WS_H2    = WS_H1 + 2048;                 // float[128]
constexpr size_t WS_NEEDED = WS_H2 + 512;

struct XP  { const float* p[5]; };
struct XPB { const unsigned short* p[5]; };

} // namespace

typedef __attribute__((ext_vector_type(8))) short short8;
typedef __attribute__((ext_vector_type(4))) float f32x4;

// ---------------------------------------------------------------------
// bf16 helpers (RNE)
// ---------------------------------------------------------------------
static __device__ __forceinline__ unsigned int rne_bf16(float x) {
    unsigned int b = __float_as_uint(x);
    return (b + 0x7fffu + ((b >> 16) & 1u)) >> 16;
}
static __device__ __forceinline__ float4 bf16x4_to_f4(uint2 u) {
    float4 f;
    f.x = __uint_as_float(u.x << 16);
    f.y = __uint_as_float(u.x & 0xffff0000u);
    f.z = __uint_as_float(u.y << 16);
    f.w = __uint_as_float(u.y & 0xffff0000u);
    return f;
}
static __device__ __forceinline__ uint2 f4_to_bf16x4(float4 v) {
    uint2 st;
    st.x = rne_bf16(v.x) | (rne_bf16(v.y) << 16);
    st.y = rne_bf16(v.z) | (rne_bf16(v.w) << 16);
    return st;
}
static __device__ __forceinline__ void fma4(float4& a, float s, const float4& b) {
    a.x += s * b.x; a.y += s * b.y; a.z += s * b.z; a.w += s * b.w;
}
static __device__ __forceinline__ void fma8(float4& alo, float4& ahi, float s, uint4 g) {
    fma4(alo, s, bf16x4_to_f4(make_uint2(g.x, g.y)));
    fma4(ahi, s, bf16x4_to_f4(make_uint2(g.z, g.w)));
}
static __device__ __forceinline__ short8 pack_af(float4 lo, float4 hi) {
    uint2 pa = f4_to_bf16x4(lo);
    uint2 pb = f4_to_bf16x4(hi);
    short8 af;
    ((unsigned int*)&af)[0] = pa.x;
    ((unsigned int*)&af)[1] = pa.y;
    ((unsigned int*)&af)[2] = pb.x;
    ((unsigned int*)&af)[3] = pb.y;
    return af;
}

// ---------------------------------------------------------------------
__global__ void k_diag(float* __restrict__ out, float v) {
    out[0] = v;
    out[1] = 0.f;
}

// ---------------------------------------------------------------------
// 0) merged prologue: [cvt inputs -> bf16 | transpose W -> bf16 | CSR row_ptr]
// ---------------------------------------------------------------------
__global__ __launch_bounds__(256) void k_prep(XP xin, unsigned short* __restrict__ b16,
                                              const float* __restrict__ Wh,
                                              unsigned short* __restrict__ WT,
                                              const int* __restrict__ rows,
                                              int* __restrict__ rptr) {
    int bx = blockIdx.x;
    if (bx < CVT_BLOCKS) {
        int q = bx * 256 + threadIdx.x;   // quad index (4 channels); grid exact
        int row = q >> 4;
        int rank = 0;
#pragma unroll
        for (int t = 1; t < 5; ++t) if (row >= XOFF[t]) rank = t;
        const float* src = xin.p[rank] + (size_t)(row - XOFF[rank]) * 64 + (q & 15) * 4;
        float4 v = *(const float4*)src;
        ((uint2*)b16)[q] = f4_to_bf16x4(v);
    } else if (bx < CVT_BLOCKS + CVTW_BLOCKS) {
        int tid = (bx - CVT_BLOCKS) * 256 + threadIdx.x;   // grid exact
        int lp = tid >> 12;
        int nk_ = tid & 4095;
        int n = nk_ >> 6;
        int k = nk_ & 63;
        float w = Wh[(size_t)lp * 4096 + k * 64 + n];
        WT[tid] = (unsigned short)rne_bf16(w);
    } else {
        int tid = (bx - CVT_BLOCKS - CVTW_BLOCKS) * 256 + threadIdx.x;
        if (tid >= PTR_TOT) return;
        int k = 0;
#pragma unroll
        for (int t = 1; t < 15; ++t) if (tid >= POFF[t]) k = t;
        int r = tid - POFF[k];
        const int* rb = rows + EOFF[k];
        int lo = 0, hi = EK[k];
        while (lo < hi) {
            int mid = (lo + hi) >> 1;
            if (rb[mid] < r) lo = mid + 1; else hi = mid;
        }
        rptr[tid] = lo;
    }
}

// ---------------------------------------------------------------------
// 2) fused aggregate (reg-direct bf16 gather) + MFMA GEMM + residual + relu
//    EXACT R12 body: one wave per 16-row tile, 4-edge batch, (64,4).
// ---------------------------------------------------------------------
__global__ __launch_bounds__(64, 4) void k_fused(XPB xp,
                                                 const int* __restrict__ cols,
                                                 const float* __restrict__ vals,
                                                 const int* __restrict__ rptr,
                                                 const unsigned short* __restrict__ WT,
                                                 unsigned short* __restrict__ xout,
                                                 int layer) {
    __shared__ float C[16 * 65];   // 4160 B, C-epilogue transpose only

    int b = blockIdx.x;
    int seg = 0;
#pragma unroll
    for (int t = 1; t < 5; ++t) if (b >= TCUM[t]) seg = t;
    int j  = TRANK[seg];
    int r0 = (b - TCUM[seg]) * 16;

    int lane = threadIdx.x;
    int m    = lane & 15;          // owned output row (A-frag m index / B-frag n index)
    int quad = lane >> 4;          // 0..3
    int s8   = quad * 8;           // channel-slice base (shorts) within a K-half

    f32x4 d0 = {0.f,0.f,0.f,0.f};
    f32x4 d1 = d0, d2 = d0, d3 = d0;

    const unsigned short* WTl = WT + (size_t)layer * 15 * 4096;
    int nk = NPJ[j];
    for (int kc = 0; kc < nk; ++kc) {
        int pk = POJ[j][kc];
        const unsigned short* __restrict__ xsrc = xp.p[PI[pk]];
        const int*   __restrict__ cb = cols + EOFF[pk];
        const float* __restrict__ vb = vals + EOFF[pk];
        const int*   __restrict__ rp = rptr + POFF[pk];

        // ---- gather this pair: 16 rows concurrently, 4-edge batch per row ----
        int ps = rp[r0 + m];
        int pe = rp[r0 + m + 1];
        float4 a0lo = make_float4(0.f,0.f,0.f,0.f), a0hi = a0lo;  // K-half 0
        float4 a1lo = a0lo, a1hi = a0lo;                          // K-half 1
        int e = ps;
        for (; e + 3 < pe; e += 4) {
            int   c0 = cb[e];
            int   c1 = cb[e + 1];
            int   c2 = cb[e + 2];
            int   c3 = cb[e + 3];
            float v0 = vb[e];
            float v1 = vb[e + 1];
            float v2 = vb[e + 2];
            float v3 = vb[e + 3];
            const unsigned short* p0 = xsrc + (size_t)c0 * 64;
            const unsigned short* p1 = xsrc + (size_t)c1 * 64;
            const unsigned short* p2 = xsrc + (size_t)c2 * 64;
            const unsigned short* p3 = xsrc + (size_t)c3 * 64;
            uint4 g00 = *(const uint4*)(p0 + s8);
            uint4 g01 = *(const uint4*)(p0 + 32 + s8);
            uint4 g10 = *(const uint4*)(p1 + s8);
            uint4 g11 = *(const uint4*)(p1 + 32 + s8);
            uint4 g20 = *(const uint4*)(p2 + s8);
            uint4 g21 = *(const uint4*)(p2 + 32 + s8);
            uint4 g30 = *(const uint4*)(p3 + s8);
            uint4 g31 = *(const uint4*)(p3 + 32 + s8);
            fma8(a0lo, a0hi, v0, g00);
            fma8(a1lo, a1hi, v0, g01);
            fma8(a0lo, a0hi, v1, g10);
            fma8(a1lo, a1hi, v1, g11);
            fma8(a0lo, a0hi, v2, g20);
            fma8(a1lo, a1hi, v2, g21);
            fma8(a0lo, a0hi, v3, g30);
            fma8(a1lo, a1hi, v3, g31);
        }
        if (e + 1 < pe) {
            int   c0 = cb[e];
            int   c1 = cb[e + 1];
            float v0 = vb[e];
            float v1 = vb[e + 1];
            const unsigned short* p0 = xsrc + (size_t)c0 * 64;
            const unsigned short* p1 = xsrc + (size_t)c1 * 64;
            uint4 g00 = *(const uint4*)(p0 + s8);
            uint4 g01 = *(const uint4*)(p0 + 32 + s8);
            uint4 g10 = *(const uint4*)(p1 + s8);
            uint4 g11 = *(const uint4*)(p1 + 32 + s8);
            fma8(a0lo, a0hi, v0, g00);
            fma8(a1lo, a1hi, v0, g01);
            fma8(a0lo, a0hi, v1, g10);
            fma8(a1lo, a1hi, v1, g11);
            e += 2;
        }
        if (e < pe) {
            int   c0 = cb[e];
            float v0 = vb[e];
            const unsigned short* p0 = xsrc + (size_t)c0 * 64;
            uint4 g00 = *(const uint4*)(p0 + s8);
            uint4 g01 = *(const uint4*)(p0 + 32 + s8);
            fma8(a0lo, a0hi, v0, g00);
            fma8(a1lo, a1hi, v0, g01);
        }
        short8 af0 = pack_af(a0lo, a0hi);   // A-frag, K-half 0 (k = quad*8+j)
        short8 af1 = pack_af(a1lo, a1hi);   // A-frag, K-half 1 (k = 32+quad*8+j)

        // ---- MFMA: D[16x64] += A[16x64] x W_k[64x64] (two 16x16x32 halves) ----
        const unsigned short* Wp = WTl + pk * 4096;
        short8 b00 = *(const short8*)(Wp + ( 0 + m) * 64 + s8);
        short8 b10 = *(const short8*)(Wp + (16 + m) * 64 + s8);
        short8 b20 = *(const short8*)(Wp + (32 + m) * 64 + s8);
        short8 b30 = *(const short8*)(Wp + (48 + m) * 64 + s8);
        d0 = __builtin_amdgcn_mfma_f32_16x16x32_bf16(af0, b00, d0, 0, 0, 0);
        d1 = __builtin_amdgcn_mfma_f32_16x16x32_bf16(af0, b10, d1, 0, 0, 0);
        d2 = __builtin_amdgcn_mfma_f32_16x16x32_bf16(af0, b20, d2, 0, 0, 0);
        d3 = __builtin_amdgcn_mfma_f32_16x16x32_bf16(af0, b30, d3, 0, 0, 0);
        short8 b01 = *(const short8*)(Wp + ( 0 + m) * 64 + 32 + s8);
        short8 b11 = *(const short8*)(Wp + (16 + m) * 64 + 32 + s8);
        short8 b21 = *(const short8*)(Wp + (32 + m) * 64 + 32 + s8);
        short8 b31 = *(const short8*)(Wp + (48 + m) * 64 + 32 + s8);
        d0 = __builtin_amdgcn_mfma_f32_16x16x32_bf16(af1, b01, d0, 0, 0, 0);
        d1 = __builtin_amdgcn_mfma_f32_16x16x32_bf16(af1, b11, d1, 0, 0, 0);
        d2 = __builtin_amdgcn_mfma_f32_16x16x32_bf16(af1, b21, d2, 0, 0, 0);
        d3 = __builtin_amdgcn_mfma_f32_16x16x32_bf16(af1, b31, d3, 0, 0, 0);
    }

    // ---- epilogue: C layout col=lane&15, row=quad*4+reg -> LDS -> coalesced ----
#pragma unroll
    for (int g = 0; g < 4; ++g) {
        C[(quad * 4 + g) * 65 +  0 + m] = d0[g];
        C[(quad * 4 + g) * 65 + 16 + m] = d1[g];
        C[(quad * 4 + g) * 65 + 32 + m] = d2[g];
        C[(quad * 4 + g) * 65 + 48 + m] = d3[g];
    }
    __builtin_amdgcn_s_waitcnt(0);   // drain lgkm before cross-lane LDS read (same wave)

    int row = lane >> 2;             // 0..15
    int qs  = lane & 3;              // 0..3 (16-channel segment)
    const float* Cr = C + row * 65 + qs * 16;
    float4 v0 = *(const float4*)(Cr + 0);
    float4 v1 = *(const float4*)(Cr + 4);
    float4 v2 = *(const float4*)(Cr + 8);
    float4 v3 = *(const float4*)(Cr + 12);
    if (layer == 2) {
        const uint4* res = (const uint4*)(xp.p[j] + (size_t)(r0 + row) * 64 + qs * 16);
        uint4 ra = res[0];
        uint4 rb = res[1];
        float4 o0 = bf16x4_to_f4(make_uint2(ra.x, ra.y));
        float4 o1 = bf16x4_to_f4(make_uint2(ra.z, ra.w));
        float4 o2 = bf16x4_to_f4(make_uint2(rb.x, rb.y));
        float4 o3 = bf16x4_to_f4(make_uint2(rb.z, rb.w));
        v0.x += o0.x; v0.y += o0.y; v0.z += o0.z; v0.w += o0.w;
        v1.x += o1.x; v1.y += o1.y; v1.z += o1.z; v1.w += o1.w;
        v2.x += o2.x; v2.y += o2.y; v2.z += o2.z; v2.w += o2.w;
        v3.x += o3.x; v3.y += o3.y; v3.z += o3.z; v3.w += o3.w;
    }
    v0.x = fmaxf(v0.x, 0.f); v0.y = fmaxf(v0.y, 0.f); v0.z = fmaxf(v0.z, 0.f); v0.w = fmaxf(v0.w, 0.f);
    v1.x = fmaxf(v1.x, 0.f); v1.y = fmaxf(v1.y, 0.f); v1.z = fmaxf(v1.z, 0.f); v1.w = fmaxf(v1.w, 0.f);
    v2.x = fmaxf(v2.x, 0.f); v2.y = fmaxf(v2.y, 0.f); v2.z = fmaxf(v2.z, 0.f); v2.w = fmaxf(v2.w, 0.f);
    v3.x = fmaxf(v3.x, 0.f); v3.y = fmaxf(v3.y, 0.f); v3.z = fmaxf(v3.z, 0.f); v3.w = fmaxf(v3.w, 0.f);
    uint2 s0 = f4_to_bf16x4(v0);
    uint2 s1 = f4_to_bf16x4(v1);
    uint2 s2 = f4_to_bf16x4(v2);
    uint2 s3 = f4_to_bf16x4(v3);
    uint4* dst = (uint4*)(xout + (size_t)(XOFF[j] + r0 + row) * 64 + qs * 16);
    dst[0] = make_uint4(s0.x, s0.y, s1.x, s1.y);
    dst[1] = make_uint4(s2.x, s2.y, s3.x, s3.y);
}

// ---------------------------------------------------------------------
// 3) pooling stage 1: per-(rank, block) partial sum/sumsq/max/min
//    uint4 loads (16B/lane, wave = 8 rows x 128B coalesced) + shfl reduce.
// ---------------------------------------------------------------------
__global__ __launch_bounds__(256) void k_pool1(const unsigned short* __restrict__ xs,
                                               double* __restrict__ psum,
                                               double* __restrict__ psq,
                                               float* __restrict__ pmax,
                                               float* __restrict__ pmin) {
    int rank = blockIdx.x >> 7;        // PB = 128
    int blk  = blockIdx.x & 127;
    int tid  = threadIdx.x;
    int rg   = tid >> 3;               // 0..31 row-group slot within block
    int cg   = tid & 7;                // channel group: channels cg*8 .. cg*8+7
    int wave = tid >> 6;
    int lane = tid & 63;

    int N = NRr[rank];
    const unsigned short* xb = xs + (size_t)XOFF[rank] * 64;

    double s[8], q[8];
    float mx[8], mn[8];
#pragma unroll
    for (int k = 0; k < 8; ++k) { s[k] = 0.0; q[k] = 0.0; mx[k] = -3.4e38f; mn[k] = 3.4e38f; }

    for (int r = blk * 32 + rg; r < N; r += PB * 32) {
        uint4 g = *(const uint4*)(xb + (size_t)r * 64 + cg * 8);
        float4 lo = bf16x4_to_f4(make_uint2(g.x, g.y));
        float4 hi = bf16x4_to_f4(make_uint2(g.z, g.w));
        float v[8] = {lo.x, lo.y, lo.z, lo.w, hi.x, hi.y, hi.z, hi.w};
#pragma unroll
        for (int k = 0; k < 8; ++k) {
            s[k] += v[k];
            q[k] += (double)v[k] * (double)v[k];
            mx[k] = fmaxf(mx[k], v[k]);
            mn[k] = fminf(mn[k], v[k]);
        }
    }

    // wave-level reduce across the 8 row-slots (lanes stride 8)
#pragma unroll
    for (int off = 8; off < 64; off <<= 1) {
#pragma unroll
        for (int k = 0; k < 8; ++k) {
            s[k] += __shfl_down(s[k], off, 64);
            q[k] += __shfl_down(q[k], off, 64);
            mx[k] = fmaxf(mx[k], __shfl_down(mx[k], off, 64));
            mn[k] = fminf(mn[k], __shfl_down(mn[k], off, 64));
        }
    }

    // cross-wave merge: lanes 0..7 of each wave hold channels lane*8+k
    __shared__ double ws_s[4][64], ws_q[4][64];
    __shared__ float  ws_mx[4][64], ws_mn[4][64];
    if (lane < 8) {
#pragma unroll
        for (int k = 0; k < 8; ++k) {
            ws_s[wave][lane * 8 + k]  = s[k];
            ws_q[wave][lane * 8 + k]  = q[k];
            ws_mx[wave][lane * 8 + k] = mx[k];
            ws_mn[wave][lane * 8 + k] = mn[k];
        }
    }
    __syncthreads();
    if (tid < 64) {
        double fs = ws_s[0][tid], fq = ws_q[0][tid];
        float fmx = ws_mx[0][tid], fmn = ws_mn[0][tid];
#pragma unroll
        for (int w = 1; w < 4; ++w) {
            fs += ws_s[w][tid]; fq += ws_q[w][tid];
            fmx = fmaxf(fmx, ws_mx[w][tid]); fmn = fminf(fmn, ws_mn[w][tid]);
        }
        int idx = (rank * PB + blk) * 64 + tid;
        psum[idx] = fs; psq[idx] = fq; pmax[idx] = fmx; pmin[idx] = fmn;
    }
}

// ---------------------------------------------------------------------
// 4) pooling stage 2 (parallel, R17-verified): 5 blocks x 256 threads.
//    Thread (chunk, c) reduces 32 partials; LDS combine in chunk order.
// ---------------------------------------------------------------------
__global__ __launch_bounds__(256) void k_pool2(const double* __restrict__ psum,
                                               const double* __restrict__ psq,
                                               const float* __restrict__ pmax,
                                               const float* __restrict__ pmin,
                                               const float* __restrict__ gf,
                                               float* __restrict__ sp) {
    __shared__ double cs[4][64], cq[4][64];
    __shared__ float  cmx[4][64], cmn[4][64];
    int rank  = blockIdx.x;
    int tid   = threadIdx.x;
    int chunk = tid >> 6;              // 0..3
    int c     = tid & 63;

    double s = 0.0, q = 0.0;
    float mx = -3.4e38f, mn = 3.4e38f;
    for (int b = chunk * 32; b < chunk * 32 + 32; ++b) {
        int idx = (rank * PB + b) * 64 + c;
        s += psum[idx]; q += psq[idx];
        mx = fmaxf(mx, pmax[idx]); mn = fminf(mn, pmin[idx]);
    }
    cs[chunk][c] = s; cq[chunk][c] = q; cmx[chunk][c] = mx; cmn[chunk][c] = mn;
    __syncthreads();
    if (chunk == 0) {
#pragma unroll
        for (int t = 1; t < 4; ++t) {
            s += cs[t][c]; q += cq[t][c];
            mx = fmaxf(mx, cmx[t][c]); mn = fminf(mn, cmn[t][c]);
        }
        double N = (double)NRr[rank];
        double mean = s / N;
        double var  = q / N - mean * mean;
        if (var < 0.0) var = 0.0;
        double sd = sqrt(var == 0.0 ? 1e-6 : var);
        sp[rank * 256 + c]       = (float)mean;
        sp[rank * 256 + 64 + c]  = (float)sd;
        sp[rank * 256 + 128 + c] = mx;
        sp[rank * 256 + 192 + c] = mn;
        if (rank == 0 && c < 4) sp[1280 + c] = gf[c];
    }
}

// ---------------------------------------------------------------------
// 5) fc1: [1,1284] @ [1284,512]. 32 blocks x 16 outputs, 16-way k-split.
// ---------------------------------------------------------------------
__global__ __launch_bounds__(256) void k_fc1(const float* __restrict__ sp,
                                             const float* __restrict__ w1,
                                             const float* __restrict__ b1,
                                             float* __restrict__ h1) {
    __shared__ float red[16][17];
    int tid = threadIdx.x;
    int oi = tid & 15;
    int ks = tid >> 4;
    int o = (blockIdx.x << 4) | oi;
    float a = 0.f;
    for (int k = ks; k < 1284; k += 16) a += sp[k] * w1[(size_t)k * 512 + o];
    red[ks][oi] = a;
    __syncthreads();
    if (tid < 16) {
        float s = 0.f;
#pragma unroll
        for (int t = 0; t < 16; ++t) s += red[t][tid];
        int oo = (blockIdx.x << 4) | tid;
        h1[oo] = fmaxf(s + b1[oo], 0.f);
    }
}

// ---------------------------------------------------------------------
// 6) fc2: [1,512] @ [512,128]. 8 blocks x 16 outputs, 16-way k-split.
//    (R12-proven parallel version; single-CU sequential merge cost ~60us.)
// ---------------------------------------------------------------------
__global__ __launch_bounds__(256) void k_fc2(const float* __restrict__ h1,
                                             const float* __restrict__ w2,
                                             const float* __restrict__ b2,
                                             float* __restrict__ h2) {
    __shared__ float red[16][17];
    int tid = threadIdx.x;
    int oi = tid & 15;
    int ks = tid >> 4;
    int o = (blockIdx.x << 4) | oi;
    float a = 0.f;
    for (int k = ks; k < 512; k += 16) a += h1[k] * w2[(size_t)k * 128 + o];
    red[ks][oi] = a;
    __syncthreads();
    if (tid < 16) {
        float s = 0.f;
#pragma unroll
        for (int t = 0; t < 16; ++t) s += red[t][tid];
        int oo = (blockIdx.x << 4) | tid;
        h2[oo] = fmaxf(s + b2[oo], 0.f);
    }
}

// ---------------------------------------------------------------------
// 7) fc3 + fc4 + output transform (tiny: 32 KB + 512 B of weights)
// ---------------------------------------------------------------------
__global__ __launch_bounds__(64) void k_rest(const float* __restrict__ h2,
                                             const float* __restrict__ w3,
                                             const float* __restrict__ b3,
                                             const float* __restrict__ w4,
                                             const float* __restrict__ b4,
                                             float* __restrict__ out) {
    __shared__ float h3[64];
    int tid = threadIdx.x;
    float a = 0.f;
    for (int k = 0; k < 128; ++k) a += h2[k] * w3[k * 64 + tid];
    h3[tid] = fmaxf(a + b3[tid], 0.f);
    __syncthreads();
    if (tid < 2) {
        float s = 0.f;
#pragma unroll
        for (int k = 0; k < 64; ++k) s += h3[k] * w4[k * 2 + tid];
        s += b4[tid];
        if (tid == 1) s = s * s;
        out[tid] = s;
    }
}

// ---------------------------------------------------------------------
extern "C" void kernel_launch(void* const* d_in, const int* in_sizes, int n_in,
                              void* d_out, int out_size, void* d_ws, size_t ws_size,
                              hipStream_t stream) {
    if (ws_size < WS_NEEDED) {
        hipLaunchKernelGGL(k_diag, dim3(1), dim3(1), 0, stream,
                           (float*)d_out, (float)(ws_size >> 20));
        return;
    }

    const float* x0   = (const float*)d_in[0];
    const float* x1   = (const float*)d_in[1];
    const float* x2   = (const float*)d_in[2];
    const float* x3   = (const float*)d_in[3];
    const float* x4   = (const float*)d_in[4];
    const int*   rows = (const int*)d_in[5];
    const int*   cols = (const int*)d_in[6];
    const float* vals = (const float*)d_in[7];
    const float* gf   = (const float*)d_in[8];
    const float* Wh   = (const float*)d_in[9];
    const float* w1   = (const float*)d_in[10];
    const float* b1   = (const float*)d_in[11];
    const float* w2   = (const float*)d_in[12];
    const float* b2   = (const float*)d_in[13];
    const float* w3   = (const float*)d_in[14];
    const float* b3   = (const float*)d_in[15];
    const float* w4   = (const float*)d_in[16];
    const float* b4   = (const float*)d_in[17];

    char* ws = (char*)d_ws;
    unsigned short* b16in = (unsigned short*)(ws + WS_B16IN);
    unsigned short* b16x  = (unsigned short*)(ws + WS_B16X);
    unsigned short* b16y  = (unsigned short*)(ws + WS_B16Y);
    int*    rptr   = (int*)(ws + WS_PTR);
    unsigned short* WT = (unsigned short*)(ws + WS_WT);
    double* psum   = (double*)(ws + WS_PSUM);
    double* psq    = (double*)(ws + WS_PSQ);
    float*  pmax   = (float*)(ws + WS_PMAX);
    float*  pmin   = (float*)(ws + WS_PMIN);
    float*  sp     = (float*)(ws + WS_SP);
    float*  h1     = (float*)(ws + WS_H1);
    float*  h2     = (float*)(ws + WS_H2);

    XP xp_in; xp_in.p[0] = x0; xp_in.p[1] = x1; xp_in.p[2] = x2; xp_in.p[3] = x3; xp_in.p[4] = x4;
    hipLaunchKernelGGL(k_prep, dim3(PREP_BLOCKS), dim3(256), 0, stream,
                       xp_in, b16in, Wh, WT, rows, rptr);

    XPB xb_in, xb_x, xb_y;
    for (int i = 0; i < 5; ++i) {
        xb_in.p[i] = b16in + (size_t)XOFF[i] * 64;
        xb_x.p[i]  = b16x  + (size_t)XOFF[i] * 64;
        xb_y.p[i]  = b16y  + (size_t)XOFF[i] * 64;
    }

    // layer 0: b16in -> b16x ; layer 1: b16x -> b16y ; layer 2: b16y -> b16x (+residual)
    hipLaunchKernelGGL(k_fused, dim3(FUSED_BLOCKS), dim3(64), 0, stream,
                       xb_in, cols, vals, rptr, WT, b16x, 0);
    hipLaunchKernelGGL(k_fused, dim3(FUSED_BLOCKS), dim3(64), 0, stream,
                       xb_x, cols, vals, rptr, WT, b16y, 1);
    hipLaunchKernelGGL(k_fused, dim3(FUSED_BLOCKS), dim3(64), 0, stream,
                       xb_y, cols, vals, rptr, WT, b16x, 2);

    hipLaunchKernelGGL(k_pool1, dim3(5 * PB), dim3(256), 0, stream, b16x, psum, psq, pmax, pmin);
    hipLaunchKernelGGL(k_pool2, dim3(5), dim3(256), 0, stream, psum, psq, pmax, pmin, gf, sp);
    hipLaunchKernelGGL(k_fc1, dim3(32), dim3(256), 0, stream, sp, w1, b1, h1);
    hipLaunchKernelGGL(k_fc2, dim3(8), dim3(256), 0, stream, h1, w2, b2, h2);
    hipLaunchKernelGGL(k_rest, dim3(1), dim3(64), 0, stream, h2, w3, b3, w4, b4, (float*)d_out);
}